// Round 1
// baseline (1685.202 us; speedup 1.0000x reference)
//
#include <hip/hip_runtime.h>

#define N_NODES  100000
#define N_EDGES  3200000
#define N_GRAPHS 1000

__device__ __forceinline__ float fast_tanh(float x) {
    // tanh(x) = 1 - 2/(exp(2x)+1); exact at saturation (exp->inf or 0)
    float e = __expf(2.0f * x);
    return 1.0f - 2.0f / (e + 1.0f);
}

// ---------------- Edge kernel: msg = tanh([n_src, e_attr] @ Wm + bm), scatter-add to x[dst]
__global__ __launch_bounds__(256) void edge_kernel(
    const int* __restrict__ ei,          // [2, E]
    const float* __restrict__ node_attr, // [N, 16]
    const float* __restrict__ edge_attr, // [E, 16]
    const float* __restrict__ Wm,        // [32, 10]
    const float* __restrict__ bm,        // [10]
    float* __restrict__ x)               // [N, 10] accumulator
{
    int e = blockIdx.x * blockDim.x + threadIdx.x;
    if (e >= N_EDGES) return;

    int src = ei[e];
    int dst = ei[N_EDGES + e];

    float in[32];
    const float4* na = reinterpret_cast<const float4*>(node_attr + (size_t)src * 16);
    const float4* ea = reinterpret_cast<const float4*>(edge_attr + (size_t)e * 16);
    #pragma unroll
    for (int q = 0; q < 4; ++q) {
        float4 v = na[q];
        in[q*4+0] = v.x; in[q*4+1] = v.y; in[q*4+2] = v.z; in[q*4+3] = v.w;
    }
    #pragma unroll
    for (int q = 0; q < 4; ++q) {
        float4 v = ea[q];
        in[16+q*4+0] = v.x; in[16+q*4+1] = v.y; in[16+q*4+2] = v.z; in[16+q*4+3] = v.w;
    }

    float acc[10];
    #pragma unroll
    for (int j = 0; j < 10; ++j) acc[j] = bm[j];   // wave-uniform -> s_load

    #pragma unroll
    for (int i = 0; i < 32; ++i) {
        float xi = in[i];
        #pragma unroll
        for (int j = 0; j < 10; ++j)
            acc[j] = fmaf(xi, Wm[i*10 + j], acc[j]); // uniform weight -> SGPR operand
    }

    float* xd = x + (size_t)dst * 10;
    #pragma unroll
    for (int j = 0; j < 10; ++j)
        atomicAdd(xd + j, fast_tanh(acc[j]));
}

// ---------------- Node kernel: h=tanh(x@W1+b1); h=tanh(h@W2+b2); scatter-add to g[batch]
__global__ __launch_bounds__(256) void node_kernel(
    const float* __restrict__ x,     // [N, 10]
    const int* __restrict__ batch,   // [N]
    const float* __restrict__ W1, const float* __restrict__ b1,  // [10,10],[10]
    const float* __restrict__ W2, const float* __restrict__ b2,  // [10,5],[5]
    float* __restrict__ g)           // [G, 5] accumulator
{
    int n = blockIdx.x * blockDim.x + threadIdx.x;
    if (n >= N_NODES) return;

    float h0[10];
    #pragma unroll
    for (int j = 0; j < 10; ++j) h0[j] = x[(size_t)n * 10 + j];

    float h1[10];
    #pragma unroll
    for (int j = 0; j < 10; ++j) h1[j] = b1[j];
    #pragma unroll
    for (int i = 0; i < 10; ++i) {
        float xi = h0[i];
        #pragma unroll
        for (int j = 0; j < 10; ++j) h1[j] = fmaf(xi, W1[i*10 + j], h1[j]);
    }
    #pragma unroll
    for (int j = 0; j < 10; ++j) h1[j] = fast_tanh(h1[j]);

    float h2[5];
    #pragma unroll
    for (int j = 0; j < 5; ++j) h2[j] = b2[j];
    #pragma unroll
    for (int i = 0; i < 10; ++i) {
        float xi = h1[i];
        #pragma unroll
        for (int j = 0; j < 5; ++j) h2[j] = fmaf(xi, W2[i*5 + j], h2[j]);
    }

    int b = batch[n];
    float* gd = g + (size_t)b * 5;
    #pragma unroll
    for (int j = 0; j < 5; ++j)
        atomicAdd(gd + j, fast_tanh(h2[j]));
}

// ---------------- Graph kernel: out = tanh(g@W3+b3) @ W4 + b4
__global__ __launch_bounds__(256) void graph_kernel(
    const float* __restrict__ g,     // [G, 5]
    const float* __restrict__ W3, const float* __restrict__ b3,  // [5,5],[5]
    const float* __restrict__ W4, const float* __restrict__ b4,  // [5,1],[1]
    float* __restrict__ out)         // [G]
{
    int i = blockIdx.x * blockDim.x + threadIdx.x;
    if (i >= N_GRAPHS) return;

    float t[5];
    #pragma unroll
    for (int j = 0; j < 5; ++j) t[j] = b3[j];
    #pragma unroll
    for (int k = 0; k < 5; ++k) {
        float gk = g[(size_t)i * 5 + k];
        #pragma unroll
        for (int j = 0; j < 5; ++j) t[j] = fmaf(gk, W3[k*5 + j], t[j]);
    }

    float o = b4[0];
    #pragma unroll
    for (int k = 0; k < 5; ++k) o = fmaf(fast_tanh(t[k]), W4[k], o);
    out[i] = o;
}

extern "C" void kernel_launch(void* const* d_in, const int* in_sizes, int n_in,
                              void* d_out, int out_size, void* d_ws, size_t ws_size,
                              hipStream_t stream) {
    const int*   ei        = (const int*)  d_in[0];
    const float* node_attr = (const float*)d_in[1];
    const float* edge_attr = (const float*)d_in[2];
    const int*   batch     = (const int*)  d_in[3];
    const float* Wm = (const float*)d_in[4];
    const float* bm = (const float*)d_in[5];
    const float* W1 = (const float*)d_in[6];
    const float* b1 = (const float*)d_in[7];
    const float* W2 = (const float*)d_in[8];
    const float* b2 = (const float*)d_in[9];
    const float* W3 = (const float*)d_in[10];
    const float* b3 = (const float*)d_in[11];
    const float* W4 = (const float*)d_in[12];
    const float* b4 = (const float*)d_in[13];

    float* x = (float*)d_ws;                                        // [N_NODES, 10]
    float* g = (float*)((char*)d_ws + (size_t)N_NODES * 10 * 4);    // [N_GRAPHS, 5]
    float* out = (float*)d_out;

    hipMemsetAsync(x, 0, (size_t)N_NODES * 10 * sizeof(float), stream);
    hipMemsetAsync(g, 0, (size_t)N_GRAPHS * 5 * sizeof(float), stream);

    edge_kernel<<<(N_EDGES + 255) / 256, 256, 0, stream>>>(
        ei, node_attr, edge_attr, Wm, bm, x);
    node_kernel<<<(N_NODES + 255) / 256, 256, 0, stream>>>(
        x, batch, W1, b1, W2, b2, g);
    graph_kernel<<<(N_GRAPHS + 255) / 256, 256, 0, stream>>>(
        g, W3, b3, W4, b4, out);
}

// Round 3
// 1677.940 us; speedup vs baseline: 1.0043x; 1.0043x over previous
//
#include <hip/hip_runtime.h>

#define N_NODES  100000
#define N_EDGES  3200000
#define N_GRAPHS 1000
#define NCOPY    8

#define XSTRIDE ((size_t)N_NODES * 10)   // floats per x copy
#define GSTRIDE ((size_t)N_GRAPHS * 5)   // floats per g copy

typedef float f32x4 __attribute__((ext_vector_type(4)));

__device__ __forceinline__ float fast_tanh(float x) {
    float e = __expf(2.0f * x);
    return 1.0f - 2.0f / (e + 1.0f);
}

// True XCD id of this wave (m09: s_getreg HW_REG_XCC_ID returns 0..7 on MI355X).
__device__ __forceinline__ int get_xcc() {
    unsigned id;
    asm("s_getreg_b32 %0, hwreg(HW_REG_XCC_ID)" : "=s"(id));
    return (int)(id & (NCOPY - 1));
}

// Plain (no sc bits) f32 atomic add -> RMW executes at the issuing XCD's L2.
// Safe ONLY because each XCD targets its private copy of the accumulator.
__device__ __forceinline__ void atomic_add_xcd(float* p, float v) {
    asm volatile("global_atomic_add_f32 %0, %1, off"
                 :
                 : "v"(p), "v"(v)
                 : "memory");
}

// ---------------- Edge kernel ----------------
template <bool PRIV>
__global__ __launch_bounds__(256) void edge_kernel(
    const int* __restrict__ ei,          // [2, E]
    const float* __restrict__ node_attr, // [N, 16]
    const float* __restrict__ edge_attr, // [E, 16]
    const float* __restrict__ Wm,        // [32, 10]
    const float* __restrict__ bm,        // [10]
    float* __restrict__ xc)              // [NCOPY][N, 10] (or [1][N,10])
{
    int e = blockIdx.x * 256 + threadIdx.x;
    if (e >= N_EDGES) return;

    int src = __builtin_nontemporal_load(ei + e);
    int dst = __builtin_nontemporal_load(ei + N_EDGES + e);

    float in[32];
    const f32x4* na = reinterpret_cast<const f32x4*>(node_attr + (size_t)src * 16);
    const f32x4* ea = reinterpret_cast<const f32x4*>(edge_attr + (size_t)e * 16);
    #pragma unroll
    for (int q = 0; q < 4; ++q) {
        f32x4 v = na[q];                                   // reused table: cacheable
        in[q*4+0] = v.x; in[q*4+1] = v.y; in[q*4+2] = v.z; in[q*4+3] = v.w;
    }
    #pragma unroll
    for (int q = 0; q < 4; ++q) {
        f32x4 v = __builtin_nontemporal_load(ea + q);      // streamed once: nt
        in[16+q*4+0] = v.x; in[16+q*4+1] = v.y; in[16+q*4+2] = v.z; in[16+q*4+3] = v.w;
    }

    float acc[10];
    #pragma unroll
    for (int j = 0; j < 10; ++j) acc[j] = bm[j];           // wave-uniform -> s_load

    #pragma unroll
    for (int i = 0; i < 32; ++i) {
        float xi = in[i];
        #pragma unroll
        for (int j = 0; j < 10; ++j)
            acc[j] = fmaf(xi, Wm[i*10 + j], acc[j]);
    }

    float* xd = xc + (PRIV ? (size_t)get_xcc() * XSTRIDE : 0) + (size_t)dst * 10;
    #pragma unroll
    for (int j = 0; j < 10; ++j) {
        float m = fast_tanh(acc[j]);
        if (PRIV) atomic_add_xcd(xd + j, m);
        else      atomicAdd(xd + j, m);
    }
}

// ---------------- Node kernel ----------------
template <bool PRIV>
__global__ __launch_bounds__(256) void node_kernel(
    const float* __restrict__ xc,    // [NCOPY][N, 10]
    const int* __restrict__ batch,   // [N]
    const float* __restrict__ W1, const float* __restrict__ b1,
    const float* __restrict__ W2, const float* __restrict__ b2,
    float* __restrict__ gc)          // [NCOPY][G, 5]
{
    int n = blockIdx.x * 256 + threadIdx.x;
    if (n >= N_NODES) return;

    float h0[10];
    #pragma unroll
    for (int j = 0; j < 10; ++j) h0[j] = 0.0f;
    #pragma unroll
    for (int c = 0; c < (PRIV ? NCOPY : 1); ++c) {
        const float* xr = xc + (size_t)c * XSTRIDE + (size_t)n * 10;
        #pragma unroll
        for (int j = 0; j < 10; ++j) h0[j] += xr[j];
    }

    float h1[10];
    #pragma unroll
    for (int j = 0; j < 10; ++j) h1[j] = b1[j];
    #pragma unroll
    for (int i = 0; i < 10; ++i) {
        float xi = h0[i];
        #pragma unroll
        for (int j = 0; j < 10; ++j) h1[j] = fmaf(xi, W1[i*10 + j], h1[j]);
    }
    #pragma unroll
    for (int j = 0; j < 10; ++j) h1[j] = fast_tanh(h1[j]);

    float h2[5];
    #pragma unroll
    for (int j = 0; j < 5; ++j) h2[j] = b2[j];
    #pragma unroll
    for (int i = 0; i < 10; ++i) {
        float xi = h1[i];
        #pragma unroll
        for (int j = 0; j < 5; ++j) h2[j] = fmaf(xi, W2[i*5 + j], h2[j]);
    }

    int b = __builtin_nontemporal_load(batch + n);
    float* gd = gc + (PRIV ? (size_t)get_xcc() * GSTRIDE : 0) + (size_t)b * 5;
    #pragma unroll
    for (int j = 0; j < 5; ++j) {
        float m = fast_tanh(h2[j]);
        if (PRIV) atomic_add_xcd(gd + j, m);
        else      atomicAdd(gd + j, m);
    }
}

// ---------------- Graph kernel ----------------
template <bool PRIV>
__global__ __launch_bounds__(256) void graph_kernel(
    const float* __restrict__ gc,    // [NCOPY][G, 5]
    const float* __restrict__ W3, const float* __restrict__ b3,
    const float* __restrict__ W4, const float* __restrict__ b4,
    float* __restrict__ out)         // [G]
{
    int i = blockIdx.x * 256 + threadIdx.x;
    if (i >= N_GRAPHS) return;

    float gs[5];
    #pragma unroll
    for (int k = 0; k < 5; ++k) gs[k] = 0.0f;
    #pragma unroll
    for (int c = 0; c < (PRIV ? NCOPY : 1); ++c) {
        const float* gr = gc + (size_t)c * GSTRIDE + (size_t)i * 5;
        #pragma unroll
        for (int k = 0; k < 5; ++k) gs[k] += gr[k];
    }

    float t[5];
    #pragma unroll
    for (int j = 0; j < 5; ++j) t[j] = b3[j];
    #pragma unroll
    for (int k = 0; k < 5; ++k) {
        float gk = gs[k];
        #pragma unroll
        for (int j = 0; j < 5; ++j) t[j] = fmaf(gk, W3[k*5 + j], t[j]);
    }

    float o = b4[0];
    #pragma unroll
    for (int k = 0; k < 5; ++k) o = fmaf(fast_tanh(t[k]), W4[k], o);
    out[i] = o;
}

extern "C" void kernel_launch(void* const* d_in, const int* in_sizes, int n_in,
                              void* d_out, int out_size, void* d_ws, size_t ws_size,
                              hipStream_t stream) {
    const int*   ei        = (const int*)  d_in[0];
    const float* node_attr = (const float*)d_in[1];
    const float* edge_attr = (const float*)d_in[2];
    const int*   batch     = (const int*)  d_in[3];
    const float* Wm = (const float*)d_in[4];
    const float* bm = (const float*)d_in[5];
    const float* W1 = (const float*)d_in[6];
    const float* b1 = (const float*)d_in[7];
    const float* W2 = (const float*)d_in[8];
    const float* b2 = (const float*)d_in[9];
    const float* W3 = (const float*)d_in[10];
    const float* b3 = (const float*)d_in[11];
    const float* W4 = (const float*)d_in[12];
    const float* b4 = (const float*)d_in[13];
    float* out = (float*)d_out;

    const size_t need_priv = (NCOPY * (XSTRIDE + GSTRIDE)) * sizeof(float); // ~32.2 MB

    if (ws_size >= need_priv) {
        float* xc = (float*)d_ws;                                   // [8][N,10]
        float* gc = xc + NCOPY * XSTRIDE;                           // [8][G,5]
        (void)hipMemsetAsync(d_ws, 0, need_priv, stream);
        edge_kernel<true><<<(N_EDGES + 255) / 256, 256, 0, stream>>>(
            ei, node_attr, edge_attr, Wm, bm, xc);
        node_kernel<true><<<(N_NODES + 255) / 256, 256, 0, stream>>>(
            xc, batch, W1, b1, W2, b2, gc);
        graph_kernel<true><<<(N_GRAPHS + 255) / 256, 256, 0, stream>>>(
            gc, W3, b3, W4, b4, out);
    } else {
        float* xc = (float*)d_ws;
        float* gc = xc + XSTRIDE;
        (void)hipMemsetAsync(d_ws, 0, (XSTRIDE + GSTRIDE) * sizeof(float), stream);
        edge_kernel<false><<<(N_EDGES + 255) / 256, 256, 0, stream>>>(
            ei, node_attr, edge_attr, Wm, bm, xc);
        node_kernel<false><<<(N_NODES + 255) / 256, 256, 0, stream>>>(
            xc, batch, W1, b1, W2, b2, gc);
        graph_kernel<false><<<(N_GRAPHS + 255) / 256, 256, 0, stream>>>(
            gc, W3, b3, W4, b4, out);
    }
}

// Round 4
// 478.045 us; speedup vs baseline: 3.5252x; 3.5100x over previous
//
#include <hip/hip_runtime.h>

#define N_NODES  100000
#define N_EDGES  3200000
#define N_GRAPHS 1000

// ---- bucketed scatter config ----
#define NPB      128                                  // nodes per bucket (pow2)
#define NB       782                                  // ceil(N_NODES/NPB)
#define CAP      4500                                 // slots/bucket: mean 4096 + 6.3 sigma
#define OVF_CAP  16384
#define BLK_E    8192                                 // edges per scatter block
#define S1_GRID  ((N_EDGES + BLK_E - 1) / BLK_E)      // 391

typedef float f32x4 __attribute__((ext_vector_type(4)));

// ---- ws layout (bytes) ----
#define CUR_OFF    0                                  // u32 cursor[NB] (pad to 1024)
#define OVFC_OFF   4096                               // u32 ovf_cnt
#define G_OFF      4352                               // float g[5000] -> ends 24352
#define ZERO_BYTES 24576                              // memset [0, ZERO_BYTES)
#define OVF_OFF    24576                              // uint2 ovf[OVF_CAP] -> ends 155648
#define SORT_OFF   163840                             // uint2 sorted[NB*CAP]
#define WS_NEED    (SORT_OFF + (size_t)NB * CAP * 8)  // ~28.3 MB

// legacy fallback sizes
#define XSTRIDE ((size_t)N_NODES * 10)
#define GSTRIDE ((size_t)N_GRAPHS * 5)

__device__ __forceinline__ float fast_tanh(float x) {
    float e = __expf(2.0f * x);
    return 1.0f - 2.0f / (e + 1.0f);
}

// ================= scatter: bucket edges by dst, counting-scatter =================
__global__ __launch_bounds__(256) void scatter_kernel(
    const int* __restrict__ ei,          // [2, E]
    uint2* __restrict__ sorted,          // [NB][CAP]
    unsigned* __restrict__ cursor,       // [NB]
    unsigned* __restrict__ ovf_cnt,
    uint2* __restrict__ ovf)
{
    __shared__ unsigned hist[NB];
    __shared__ unsigned lbase[NB];
    const int tid = threadIdx.x;
    const int e0  = blockIdx.x * BLK_E;

    for (int b = tid; b < NB; b += 256) hist[b] = 0u;
    __syncthreads();

    int dcache[BLK_E / 256];
    #pragma unroll
    for (int k = 0; k < BLK_E / 256; ++k) {
        int e = e0 + k * 256 + tid;
        int d = (e < N_EDGES) ? __builtin_nontemporal_load(ei + N_EDGES + e) : -1;
        dcache[k] = d;
        if (d >= 0) atomicAdd(&hist[d >> 7], 1u);
    }
    __syncthreads();

    for (int b = tid; b < NB; b += 256) {
        unsigned c = hist[b];
        lbase[b] = c ? atomicAdd(cursor + b, c) : 0u;   // reserve contiguous span
        hist[b] = 0u;                                   // reuse as local cursor
    }
    __syncthreads();

    #pragma unroll
    for (int k = 0; k < BLK_E / 256; ++k) {
        int d = dcache[k];
        if (d < 0) continue;
        int e = e0 + k * 256 + tid;
        int s = __builtin_nontemporal_load(ei + e);
        int bk = d >> 7;
        unsigned pos = lbase[bk] + atomicAdd(&hist[bk], 1u);
        uint2 ent;
        ent.x = (unsigned)e | ((unsigned)bk << 22);           // eid:22 | bucket:10
        ent.y = (unsigned)s | ((unsigned)(d & 127) << 17);    // src:17 | dst_local:7
        if (pos < CAP) {
            sorted[(size_t)bk * CAP + pos] = ent;
        } else {
            unsigned op = atomicAdd(ovf_cnt, 1u);
            if (op < OVF_CAP) ovf[op] = ent;
        }
    }
}

// ================= per-bucket: gather edges, message MLP, LDS segment-sum,
//                   fused node MLP + graph pooling =================
__device__ __forceinline__ void accumulate_edge(
    uint2 ent, const float* __restrict__ node_attr, const float* __restrict__ edge_attr,
    const float* __restrict__ Wm, const float* __restrict__ bm, float (*acc)[10])
{
    unsigned eid = ent.x & 0x3FFFFFu;
    unsigned src = ent.y & 0x1FFFFu;
    unsigned dl  = (ent.y >> 17) & 0x7Fu;

    float in[32];
    const f32x4* na = reinterpret_cast<const f32x4*>(node_attr + (size_t)src * 16);
    const f32x4* ea = reinterpret_cast<const f32x4*>(edge_attr + (size_t)eid * 16);
    #pragma unroll
    for (int q = 0; q < 4; ++q) {
        f32x4 v = na[q];                               // hot 6.4 MB table: cacheable
        in[q*4+0] = v.x; in[q*4+1] = v.y; in[q*4+2] = v.z; in[q*4+3] = v.w;
    }
    #pragma unroll
    for (int q = 0; q < 4; ++q) {
        f32x4 v = __builtin_nontemporal_load(ea + q);  // each row read once: nt
        in[16+q*4+0] = v.x; in[16+q*4+1] = v.y; in[16+q*4+2] = v.z; in[16+q*4+3] = v.w;
    }

    float m[10];
    #pragma unroll
    for (int j = 0; j < 10; ++j) m[j] = bm[j];
    #pragma unroll
    for (int i = 0; i < 32; ++i) {
        float xi = in[i];
        #pragma unroll
        for (int j = 0; j < 10; ++j) m[j] = fmaf(xi, Wm[i*10 + j], m[j]);
    }
    #pragma unroll
    for (int j = 0; j < 10; ++j)
        atomicAdd(&acc[dl][j], fast_tanh(m[j]));       // LDS atomic
}

__global__ __launch_bounds__(256) void bucket_kernel(
    const uint2* __restrict__ sorted, const unsigned* __restrict__ cursor,
    const unsigned* __restrict__ ovf_cnt, const uint2* __restrict__ ovf,
    const float* __restrict__ node_attr, const float* __restrict__ edge_attr,
    const int* __restrict__ batch,
    const float* __restrict__ Wm, const float* __restrict__ bm,
    const float* __restrict__ W1, const float* __restrict__ b1,
    const float* __restrict__ W2, const float* __restrict__ b2,
    float* __restrict__ g)
{
    __shared__ float acc[NPB][10];                     // 5.12 KB node accumulator
    __shared__ float gacc[64][5];                      // per-graph partials
    __shared__ int bse[2];
    const int tid = threadIdx.x;
    const int b   = blockIdx.x;

    for (int i = tid; i < NPB * 10; i += 256) ((float*)acc)[i] = 0.0f;
    __syncthreads();

    const unsigned cnt = min(cursor[b], (unsigned)CAP);
    const uint2* base = sorted + (size_t)b * CAP;
    for (unsigned i = tid; i < cnt; i += 256)
        accumulate_edge(base[i], node_attr, edge_attr, Wm, bm, acc);
    __syncthreads();

    // overflow entries (normally zero)
    unsigned L = min(*ovf_cnt, (unsigned)OVF_CAP);
    if (L) {
        for (unsigned i = tid; i < L; i += 256) {
            uint2 ent = ovf[i];
            if ((ent.x >> 22) == (unsigned)b)
                accumulate_edge(ent, node_attr, edge_attr, Wm, bm, acc);
        }
        __syncthreads();
    }

    // graph-range of this block's nodes (batch is sorted)
    if (tid == 0) {
        int nfirst = b * NPB;
        int nlast  = min(nfirst + NPB - 1, N_NODES - 1);
        bse[0] = batch[nfirst];
        bse[1] = batch[nlast];
    }
    __syncthreads();
    const int bmin = bse[0];
    const int R    = bse[1] - bse[0] + 1;
    const bool lds_pool = (R <= 64);
    if (lds_pool)
        for (int i = tid; i < R * 5; i += 256) ((float*)gacc)[i] = 0.0f;
    __syncthreads();

    // fused node MLP: x never leaves LDS
    const int n = b * NPB + tid;
    if (tid < NPB && n < N_NODES) {
        float h0[10];
        #pragma unroll
        for (int j = 0; j < 10; ++j) h0[j] = acc[tid][j];

        float h1[10];
        #pragma unroll
        for (int j = 0; j < 10; ++j) h1[j] = b1[j];
        #pragma unroll
        for (int i = 0; i < 10; ++i) {
            float xi = h0[i];
            #pragma unroll
            for (int j = 0; j < 10; ++j) h1[j] = fmaf(xi, W1[i*10 + j], h1[j]);
        }
        #pragma unroll
        for (int j = 0; j < 10; ++j) h1[j] = fast_tanh(h1[j]);

        float h2[5];
        #pragma unroll
        for (int j = 0; j < 5; ++j) h2[j] = b2[j];
        #pragma unroll
        for (int i = 0; i < 10; ++i) {
            float xi = h1[i];
            #pragma unroll
            for (int j = 0; j < 5; ++j) h2[j] = fmaf(xi, W2[i*5 + j], h2[j]);
        }

        const int bg = batch[n];
        if (lds_pool) {
            #pragma unroll
            for (int j = 0; j < 5; ++j) atomicAdd(&gacc[bg - bmin][j], fast_tanh(h2[j]));
        } else {
            #pragma unroll
            for (int j = 0; j < 5; ++j) atomicAdd(g + (size_t)bg * 5 + j, fast_tanh(h2[j]));
        }
    }
    __syncthreads();

    if (lds_pool) {
        for (int i = tid; i < R * 5; i += 256) {
            float v = ((float*)gacc)[i];
            if (v != 0.0f) atomicAdd(g + (size_t)bmin * 5 + i, v);
        }
    }
}

// ================= graph head =================
__global__ __launch_bounds__(256) void graph_kernel(
    const float* __restrict__ g,
    const float* __restrict__ W3, const float* __restrict__ b3,
    const float* __restrict__ W4, const float* __restrict__ b4,
    float* __restrict__ out)
{
    int i = blockIdx.x * 256 + threadIdx.x;
    if (i >= N_GRAPHS) return;

    float t[5];
    #pragma unroll
    for (int j = 0; j < 5; ++j) t[j] = b3[j];
    #pragma unroll
    for (int k = 0; k < 5; ++k) {
        float gk = g[(size_t)i * 5 + k];
        #pragma unroll
        for (int j = 0; j < 5; ++j) t[j] = fmaf(gk, W3[k*5 + j], t[j]);
    }
    float o = b4[0];
    #pragma unroll
    for (int k = 0; k < 5; ++k) o = fmaf(fast_tanh(t[k]), W4[k], o);
    out[i] = o;
}

// ================= legacy atomic fallback (ws too small) =================
__global__ __launch_bounds__(256) void edge_kernel_legacy(
    const int* __restrict__ ei, const float* __restrict__ node_attr,
    const float* __restrict__ edge_attr, const float* __restrict__ Wm,
    const float* __restrict__ bm, float* __restrict__ x)
{
    int e = blockIdx.x * 256 + threadIdx.x;
    if (e >= N_EDGES) return;
    int src = ei[e], dst = ei[N_EDGES + e];
    float in[32];
    const f32x4* na = reinterpret_cast<const f32x4*>(node_attr + (size_t)src * 16);
    const f32x4* ea = reinterpret_cast<const f32x4*>(edge_attr + (size_t)e * 16);
    #pragma unroll
    for (int q = 0; q < 4; ++q) { f32x4 v = na[q];
        in[q*4]=v.x; in[q*4+1]=v.y; in[q*4+2]=v.z; in[q*4+3]=v.w; }
    #pragma unroll
    for (int q = 0; q < 4; ++q) { f32x4 v = ea[q];
        in[16+q*4]=v.x; in[16+q*4+1]=v.y; in[16+q*4+2]=v.z; in[16+q*4+3]=v.w; }
    float m[10];
    #pragma unroll
    for (int j = 0; j < 10; ++j) m[j] = bm[j];
    #pragma unroll
    for (int i = 0; i < 32; ++i) {
        float xi = in[i];
        #pragma unroll
        for (int j = 0; j < 10; ++j) m[j] = fmaf(xi, Wm[i*10+j], m[j]);
    }
    float* xd = x + (size_t)dst * 10;
    #pragma unroll
    for (int j = 0; j < 10; ++j) atomicAdd(xd + j, fast_tanh(m[j]));
}

__global__ __launch_bounds__(256) void node_kernel_legacy(
    const float* __restrict__ x, const int* __restrict__ batch,
    const float* __restrict__ W1, const float* __restrict__ b1,
    const float* __restrict__ W2, const float* __restrict__ b2,
    float* __restrict__ g)
{
    int n = blockIdx.x * 256 + threadIdx.x;
    if (n >= N_NODES) return;
    float h1[10];
    #pragma unroll
    for (int j = 0; j < 10; ++j) h1[j] = b1[j];
    #pragma unroll
    for (int i = 0; i < 10; ++i) {
        float xi = x[(size_t)n * 10 + i];
        #pragma unroll
        for (int j = 0; j < 10; ++j) h1[j] = fmaf(xi, W1[i*10+j], h1[j]);
    }
    #pragma unroll
    for (int j = 0; j < 10; ++j) h1[j] = fast_tanh(h1[j]);
    float h2[5];
    #pragma unroll
    for (int j = 0; j < 5; ++j) h2[j] = b2[j];
    #pragma unroll
    for (int i = 0; i < 10; ++i) {
        float xi = h1[i];
        #pragma unroll
        for (int j = 0; j < 5; ++j) h2[j] = fmaf(xi, W2[i*5+j], h2[j]);
    }
    int bg = batch[n];
    #pragma unroll
    for (int j = 0; j < 5; ++j) atomicAdd(g + (size_t)bg * 5 + j, fast_tanh(h2[j]));
}

extern "C" void kernel_launch(void* const* d_in, const int* in_sizes, int n_in,
                              void* d_out, int out_size, void* d_ws, size_t ws_size,
                              hipStream_t stream) {
    const int*   ei        = (const int*)  d_in[0];
    const float* node_attr = (const float*)d_in[1];
    const float* edge_attr = (const float*)d_in[2];
    const int*   batch     = (const int*)  d_in[3];
    const float* Wm = (const float*)d_in[4];
    const float* bm = (const float*)d_in[5];
    const float* W1 = (const float*)d_in[6];
    const float* b1 = (const float*)d_in[7];
    const float* W2 = (const float*)d_in[8];
    const float* b2 = (const float*)d_in[9];
    const float* W3 = (const float*)d_in[10];
    const float* b3 = (const float*)d_in[11];
    const float* W4 = (const float*)d_in[12];
    const float* b4 = (const float*)d_in[13];
    float* out = (float*)d_out;
    char* ws = (char*)d_ws;

    if (ws_size >= WS_NEED) {
        unsigned* cursor  = (unsigned*)(ws + CUR_OFF);
        unsigned* ovf_cnt = (unsigned*)(ws + OVFC_OFF);
        float*    g       = (float*)   (ws + G_OFF);
        uint2*    ovf     = (uint2*)   (ws + OVF_OFF);
        uint2*    sorted  = (uint2*)   (ws + SORT_OFF);

        (void)hipMemsetAsync(ws, 0, ZERO_BYTES, stream);
        scatter_kernel<<<S1_GRID, 256, 0, stream>>>(ei, sorted, cursor, ovf_cnt, ovf);
        bucket_kernel<<<NB, 256, 0, stream>>>(sorted, cursor, ovf_cnt, ovf,
                                              node_attr, edge_attr, batch,
                                              Wm, bm, W1, b1, W2, b2, g);
        graph_kernel<<<(N_GRAPHS + 255) / 256, 256, 0, stream>>>(g, W3, b3, W4, b4, out);
    } else {
        float* x = (float*)ws;
        float* g = x + XSTRIDE;
        (void)hipMemsetAsync(ws, 0, (XSTRIDE + GSTRIDE) * sizeof(float), stream);
        edge_kernel_legacy<<<(N_EDGES + 255) / 256, 256, 0, stream>>>(
            ei, node_attr, edge_attr, Wm, bm, x);
        node_kernel_legacy<<<(N_NODES + 255) / 256, 256, 0, stream>>>(
            x, batch, W1, b1, W2, b2, g);
        graph_kernel<<<(N_GRAPHS + 255) / 256, 256, 0, stream>>>(
            g, W3, b3, W4, b4, out);
    }
}

// Round 5
// 377.981 us; speedup vs baseline: 4.4584x; 1.2647x over previous
//
#include <hip/hip_runtime.h>

#define N_NODES  100000
#define N_EDGES  3200000
#define N_GRAPHS 1000

// ---- bucketed scatter config ----
#define NPB      128                                  // nodes per bucket (pow2)
#define NB       782                                  // ceil(N_NODES/NPB)
#define CAP      4500                                 // slots/bucket: mean 4096 + 6.3 sigma
#define OVF_CAP  16384
#define BLK_E    8192                                 // edges per scatter block
#define S1_GRID  ((N_EDGES + BLK_E - 1) / BLK_E)      // 391
#define S1_T     1024                                 // scatter threads/block
#define BK_T     1024                                 // bucket threads/block

typedef float f32x4 __attribute__((ext_vector_type(4)));

// ---- ws layout (bytes) ----
#define CUR_OFF    0                                  // u32 cursor[NB] (pad to 4096)
#define OVFC_OFF   4096                               // u32 ovf_cnt
#define G_OFF      4352                               // float g[5000] -> ends 24352
#define ZERO_BYTES 24576                              // memset [0, ZERO_BYTES)
#define OVF_OFF    24576                              // uint2 ovf[OVF_CAP] -> ends 155648
#define SORT_OFF   163840                             // uint2 sorted[NB*CAP]
#define WS_NEED    (SORT_OFF + (size_t)NB * CAP * 8)  // ~28.3 MB

// legacy fallback sizes
#define XSTRIDE ((size_t)N_NODES * 10)
#define GSTRIDE ((size_t)N_GRAPHS * 5)

__device__ __forceinline__ float fast_tanh(float x) {
    float e = __expf(2.0f * x);
    return 1.0f - 2.0f / (e + 1.0f);
}

// ================= scatter: bucket edges by dst, counting-scatter =================
__global__ __launch_bounds__(S1_T) void scatter_kernel(
    const int* __restrict__ ei,          // [2, E]
    uint2* __restrict__ sorted,          // [NB][CAP]
    unsigned* __restrict__ cursor,       // [NB]
    unsigned* __restrict__ ovf_cnt,
    uint2* __restrict__ ovf)
{
    __shared__ unsigned hist[NB];
    __shared__ unsigned lbase[NB];
    const int tid = threadIdx.x;
    const int e0  = blockIdx.x * BLK_E;

    for (int b = tid; b < NB; b += S1_T) hist[b] = 0u;
    __syncthreads();

    int dcache[BLK_E / S1_T];
    #pragma unroll
    for (int k = 0; k < BLK_E / S1_T; ++k) {
        int e = e0 + k * S1_T + tid;
        int d = (e < N_EDGES) ? __builtin_nontemporal_load(ei + N_EDGES + e) : -1;
        dcache[k] = d;
        if (d >= 0) atomicAdd(&hist[d >> 7], 1u);
    }
    __syncthreads();

    for (int b = tid; b < NB; b += S1_T) {
        unsigned c = hist[b];
        lbase[b] = c ? atomicAdd(cursor + b, c) : 0u;   // reserve contiguous span
        hist[b] = 0u;                                   // reuse as local cursor
    }
    __syncthreads();

    #pragma unroll
    for (int k = 0; k < BLK_E / S1_T; ++k) {
        int d = dcache[k];
        if (d < 0) continue;
        int e = e0 + k * S1_T + tid;
        int s = __builtin_nontemporal_load(ei + e);
        int bk = d >> 7;
        unsigned pos = lbase[bk] + atomicAdd(&hist[bk], 1u);
        uint2 ent;
        ent.x = (unsigned)e | ((unsigned)bk << 22);           // eid:22 | bucket:10
        ent.y = (unsigned)s | ((unsigned)(d & 127) << 17);    // src:17 | dst_local:7
        if (pos < CAP) {
            sorted[(size_t)bk * CAP + pos] = ent;
        } else {
            unsigned op = atomicAdd(ovf_cnt, 1u);
            if (op < OVF_CAP) ovf[op] = ent;
        }
    }
}

// ================= per-bucket: gather edges, message MLP, LDS segment-sum,
//                   fused node MLP + graph pooling =================
__device__ __forceinline__ void accumulate_edge(
    uint2 ent, const float* __restrict__ node_attr, const float* __restrict__ edge_attr,
    const float* __restrict__ Wm, const float* __restrict__ bm, float (*acc)[10])
{
    unsigned eid = ent.x & 0x3FFFFFu;
    unsigned src = ent.y & 0x1FFFFu;
    unsigned dl  = (ent.y >> 17) & 0x7Fu;

    float in[32];
    const f32x4* na = reinterpret_cast<const f32x4*>(node_attr + (size_t)src * 16);
    const f32x4* ea = reinterpret_cast<const f32x4*>(edge_attr + (size_t)eid * 16);
    #pragma unroll
    for (int q = 0; q < 4; ++q) {
        f32x4 v = na[q];                               // hot 6.4 MB table: cacheable
        in[q*4+0] = v.x; in[q*4+1] = v.y; in[q*4+2] = v.z; in[q*4+3] = v.w;
    }
    #pragma unroll
    for (int q = 0; q < 4; ++q) {
        f32x4 v = __builtin_nontemporal_load(ea + q);  // each row read once: nt
        in[16+q*4+0] = v.x; in[16+q*4+1] = v.y; in[16+q*4+2] = v.z; in[16+q*4+3] = v.w;
    }

    float m[10];
    #pragma unroll
    for (int j = 0; j < 10; ++j) m[j] = bm[j];
    #pragma unroll
    for (int i = 0; i < 32; ++i) {
        float xi = in[i];
        #pragma unroll
        for (int j = 0; j < 10; ++j) m[j] = fmaf(xi, Wm[i*10 + j], m[j]);
    }
    #pragma unroll
    for (int j = 0; j < 10; ++j)
        atomicAdd(&acc[dl][j], fast_tanh(m[j]));       // LDS atomic
}

__global__ __launch_bounds__(BK_T, 8) void bucket_kernel(
    const uint2* __restrict__ sorted, const unsigned* __restrict__ cursor,
    const unsigned* __restrict__ ovf_cnt, const uint2* __restrict__ ovf,
    const float* __restrict__ node_attr, const float* __restrict__ edge_attr,
    const int* __restrict__ batch,
    const float* __restrict__ Wm, const float* __restrict__ bm,
    const float* __restrict__ W1, const float* __restrict__ b1,
    const float* __restrict__ W2, const float* __restrict__ b2,
    float* __restrict__ g)
{
    __shared__ float acc[NPB][10];                     // 5.12 KB node accumulator
    __shared__ float gacc[64][5];                      // per-graph partials
    __shared__ int bse[2];
    const int tid = threadIdx.x;
    const int b   = blockIdx.x;

    for (int i = tid; i < NPB * 10; i += BK_T) ((float*)acc)[i] = 0.0f;
    __syncthreads();

    const unsigned cnt = min(cursor[b], (unsigned)CAP);
    const uint2* base = sorted + (size_t)b * CAP;

    // strided edge loop with next-entry prefetch (entry load of i+1 overlaps
    // the dependent gathers/MLP of i)
    {
        unsigned i = tid;
        bool valid = (i < cnt);
        uint2 ent = valid ? base[i] : make_uint2(0u, 0u);
        while (valid) {
            unsigned inext = i + BK_T;
            bool vnext = (inext < cnt);
            uint2 entn = vnext ? base[inext] : make_uint2(0u, 0u);
            accumulate_edge(ent, node_attr, edge_attr, Wm, bm, acc);
            i = inext; ent = entn; valid = vnext;
        }
    }
    __syncthreads();

    // overflow entries (normally zero)
    unsigned L = min(*ovf_cnt, (unsigned)OVF_CAP);
    if (L) {
        for (unsigned i = tid; i < L; i += BK_T) {
            uint2 ent = ovf[i];
            if ((ent.x >> 22) == (unsigned)b)
                accumulate_edge(ent, node_attr, edge_attr, Wm, bm, acc);
        }
        __syncthreads();
    }

    // graph-range of this block's nodes (batch is sorted)
    if (tid == 0) {
        int nfirst = b * NPB;
        int nlast  = min(nfirst + NPB - 1, N_NODES - 1);
        bse[0] = batch[nfirst];
        bse[1] = batch[nlast];
    }
    __syncthreads();
    const int bmin = bse[0];
    const int R    = bse[1] - bse[0] + 1;
    const bool lds_pool = (R <= 64);
    if (lds_pool)
        for (int i = tid; i < R * 5; i += BK_T) ((float*)gacc)[i] = 0.0f;
    __syncthreads();

    // fused node MLP: x never leaves LDS
    const int n = b * NPB + tid;
    if (tid < NPB && n < N_NODES) {
        float h0[10];
        #pragma unroll
        for (int j = 0; j < 10; ++j) h0[j] = acc[tid][j];

        float h1[10];
        #pragma unroll
        for (int j = 0; j < 10; ++j) h1[j] = b1[j];
        #pragma unroll
        for (int i = 0; i < 10; ++i) {
            float xi = h0[i];
            #pragma unroll
            for (int j = 0; j < 10; ++j) h1[j] = fmaf(xi, W1[i*10 + j], h1[j]);
        }
        #pragma unroll
        for (int j = 0; j < 10; ++j) h1[j] = fast_tanh(h1[j]);

        float h2[5];
        #pragma unroll
        for (int j = 0; j < 5; ++j) h2[j] = b2[j];
        #pragma unroll
        for (int i = 0; i < 10; ++i) {
            float xi = h1[i];
            #pragma unroll
            for (int j = 0; j < 5; ++j) h2[j] = fmaf(xi, W2[i*5 + j], h2[j]);
        }

        const int bg = batch[n];
        if (lds_pool) {
            #pragma unroll
            for (int j = 0; j < 5; ++j) atomicAdd(&gacc[bg - bmin][j], fast_tanh(h2[j]));
        } else {
            #pragma unroll
            for (int j = 0; j < 5; ++j) atomicAdd(g + (size_t)bg * 5 + j, fast_tanh(h2[j]));
        }
    }
    __syncthreads();

    if (lds_pool) {
        for (int i = tid; i < R * 5; i += BK_T) {
            float v = ((float*)gacc)[i];
            if (v != 0.0f) atomicAdd(g + (size_t)bmin * 5 + i, v);
        }
    }
}

// ================= graph head =================
__global__ __launch_bounds__(256) void graph_kernel(
    const float* __restrict__ g,
    const float* __restrict__ W3, const float* __restrict__ b3,
    const float* __restrict__ W4, const float* __restrict__ b4,
    float* __restrict__ out)
{
    int i = blockIdx.x * 256 + threadIdx.x;
    if (i >= N_GRAPHS) return;

    float t[5];
    #pragma unroll
    for (int j = 0; j < 5; ++j) t[j] = b3[j];
    #pragma unroll
    for (int k = 0; k < 5; ++k) {
        float gk = g[(size_t)i * 5 + k];
        #pragma unroll
        for (int j = 0; j < 5; ++j) t[j] = fmaf(gk, W3[k*5 + j], t[j]);
    }
    float o = b4[0];
    #pragma unroll
    for (int k = 0; k < 5; ++k) o = fmaf(fast_tanh(t[k]), W4[k], o);
    out[i] = o;
}

// ================= legacy atomic fallback (ws too small) =================
__global__ __launch_bounds__(256) void edge_kernel_legacy(
    const int* __restrict__ ei, const float* __restrict__ node_attr,
    const float* __restrict__ edge_attr, const float* __restrict__ Wm,
    const float* __restrict__ bm, float* __restrict__ x)
{
    int e = blockIdx.x * 256 + threadIdx.x;
    if (e >= N_EDGES) return;
    int src = ei[e], dst = ei[N_EDGES + e];
    float in[32];
    const f32x4* na = reinterpret_cast<const f32x4*>(node_attr + (size_t)src * 16);
    const f32x4* ea = reinterpret_cast<const f32x4*>(edge_attr + (size_t)e * 16);
    #pragma unroll
    for (int q = 0; q < 4; ++q) { f32x4 v = na[q];
        in[q*4]=v.x; in[q*4+1]=v.y; in[q*4+2]=v.z; in[q*4+3]=v.w; }
    #pragma unroll
    for (int q = 0; q < 4; ++q) { f32x4 v = ea[q];
        in[16+q*4]=v.x; in[16+q*4+1]=v.y; in[16+q*4+2]=v.z; in[16+q*4+3]=v.w; }
    float m[10];
    #pragma unroll
    for (int j = 0; j < 10; ++j) m[j] = bm[j];
    #pragma unroll
    for (int i = 0; i < 32; ++i) {
        float xi = in[i];
        #pragma unroll
        for (int j = 0; j < 10; ++j) m[j] = fmaf(xi, Wm[i*10+j], m[j]);
    }
    float* xd = x + (size_t)dst * 10;
    #pragma unroll
    for (int j = 0; j < 10; ++j) atomicAdd(xd + j, fast_tanh(m[j]));
}

__global__ __launch_bounds__(256) void node_kernel_legacy(
    const float* __restrict__ x, const int* __restrict__ batch,
    const float* __restrict__ W1, const float* __restrict__ b1,
    const float* __restrict__ W2, const float* __restrict__ b2,
    float* __restrict__ g)
{
    int n = blockIdx.x * 256 + threadIdx.x;
    if (n >= N_NODES) return;
    float h1[10];
    #pragma unroll
    for (int j = 0; j < 10; ++j) h1[j] = b1[j];
    #pragma unroll
    for (int i = 0; i < 10; ++i) {
        float xi = x[(size_t)n * 10 + i];
        #pragma unroll
        for (int j = 0; j < 10; ++j) h1[j] = fmaf(xi, W1[i*10+j], h1[j]);
    }
    #pragma unroll
    for (int j = 0; j < 10; ++j) h1[j] = fast_tanh(h1[j]);
    float h2[5];
    #pragma unroll
    for (int j = 0; j < 5; ++j) h2[j] = b2[j];
    #pragma unroll
    for (int i = 0; i < 10; ++i) {
        float xi = h1[i];
        #pragma unroll
        for (int j = 0; j < 5; ++j) h2[j] = fmaf(xi, W2[i*5+j], h2[j]);
    }
    int bg = batch[n];
    #pragma unroll
    for (int j = 0; j < 5; ++j) atomicAdd(g + (size_t)bg * 5 + j, fast_tanh(h2[j]));
}

extern "C" void kernel_launch(void* const* d_in, const int* in_sizes, int n_in,
                              void* d_out, int out_size, void* d_ws, size_t ws_size,
                              hipStream_t stream) {
    const int*   ei        = (const int*)  d_in[0];
    const float* node_attr = (const float*)d_in[1];
    const float* edge_attr = (const float*)d_in[2];
    const int*   batch     = (const int*)  d_in[3];
    const float* Wm = (const float*)d_in[4];
    const float* bm = (const float*)d_in[5];
    const float* W1 = (const float*)d_in[6];
    const float* b1 = (const float*)d_in[7];
    const float* W2 = (const float*)d_in[8];
    const float* b2 = (const float*)d_in[9];
    const float* W3 = (const float*)d_in[10];
    const float* b3 = (const float*)d_in[11];
    const float* W4 = (const float*)d_in[12];
    const float* b4 = (const float*)d_in[13];
    float* out = (float*)d_out;
    char* ws = (char*)d_ws;

    if (ws_size >= WS_NEED) {
        unsigned* cursor  = (unsigned*)(ws + CUR_OFF);
        unsigned* ovf_cnt = (unsigned*)(ws + OVFC_OFF);
        float*    g       = (float*)   (ws + G_OFF);
        uint2*    ovf     = (uint2*)   (ws + OVF_OFF);
        uint2*    sorted  = (uint2*)   (ws + SORT_OFF);

        (void)hipMemsetAsync(ws, 0, ZERO_BYTES, stream);
        scatter_kernel<<<S1_GRID, S1_T, 0, stream>>>(ei, sorted, cursor, ovf_cnt, ovf);
        bucket_kernel<<<NB, BK_T, 0, stream>>>(sorted, cursor, ovf_cnt, ovf,
                                               node_attr, edge_attr, batch,
                                               Wm, bm, W1, b1, W2, b2, g);
        graph_kernel<<<(N_GRAPHS + 255) / 256, 256, 0, stream>>>(g, W3, b3, W4, b4, out);
    } else {
        float* x = (float*)ws;
        float* g = x + XSTRIDE;
        (void)hipMemsetAsync(ws, 0, (XSTRIDE + GSTRIDE) * sizeof(float), stream);
        edge_kernel_legacy<<<(N_EDGES + 255) / 256, 256, 0, stream>>>(
            ei, node_attr, edge_attr, Wm, bm, x);
        node_kernel_legacy<<<(N_NODES + 255) / 256, 256, 0, stream>>>(
            x, batch, W1, b1, W2, b2, g);
        graph_kernel<<<(N_GRAPHS + 255) / 256, 256, 0, stream>>>(
            g, W3, b3, W4, b4, out);
    }
}